// Round 1
// baseline (76.784 us; speedup 1.0000x reference)
//
#include <hip/hip_runtime.h>

// QuantumLayer: 4-qubit, 4-layer VQC over batch B.
// R7 = R6 structure (full unroll, 2 elems/thread in v2f -> v_pk_fma_f32) with:
//  1) __launch_bounds__(256, 4): cap VGPR at 128 so all 4096 waves are
//     co-resident (4 waves/SIMD exactly) -- kills the 3-resident/4-needed
//     occupancy tail of the (256,3) build.
//  2) register diet: measurement folds |amp|^2 into the first butterfly
//     level (no live p[16] array), state regs die as consumed.
//  3) layer-3 gate build specialized: RZ dropped there => M real (ai=bi=0),
//     make_g2_real = 2 ds_read_b64 + 4 pk ops instead of 4 + 8.
// State indexing: flat k = w0*8 + w1*4 + w2*2 + w3  (wire i -> bit (3-i)).

typedef float v2f __attribute__((ext_vector_type(2)));

// G = M * RX(cx, sx) is SU(2): G = [[g, d], [-conj(d), conj(g)]].
// Msh entries are splatted v2f in LDS -> ds_read_b64 gives a VGPR pair that
// feeds VOP3P directly.
__device__ __forceinline__ void make_g2(const v2f* Msh, int idx,
                                        v2f cxv, v2f sxv,
                                        v2f& gr, v2f& gi, v2f& dr, v2f& di) {
  v2f ar = Msh[idx * 4 + 0], ai = Msh[idx * 4 + 1];
  v2f br = Msh[idx * 4 + 2], bi = Msh[idx * 4 + 3];
  gr = ar * cxv + bi * sxv;
  gi = ai * cxv - br * sxv;
  dr = ai * sxv + br * cxv;
  di = bi * cxv - ar * sxv;
}

// Layer-3 variant: RZ == I there, so M = RY is REAL (ai = bi = 0).
__device__ __forceinline__ void make_g2_real(const v2f* Msh, int idx,
                                             v2f cxv, v2f sxv,
                                             v2f& gr, v2f& gi, v2f& dr, v2f& di) {
  v2f ar = Msh[idx * 4 + 0];
  v2f br = Msh[idx * 4 + 2];
  gr = ar * cxv;
  gi = -(br * sxv);
  dr = br * cxv;
  di = -(ar * sxv);
}

// Apply SU(2) gate [[g,d],[-conj(d),conj(g)]] on wire W (bit 3-W).
template <int W>
__device__ __forceinline__ void apply_su2(v2f (&sr)[16], v2f (&si)[16],
                                          v2f gr, v2f gi, v2f dr, v2f di) {
  constexpr int stride = 8 >> W;
#pragma unroll
  for (int base = 0; base < 16; base += 2 * stride) {
#pragma unroll
    for (int j = 0; j < stride; ++j) {
      const int k0 = base + j, k1 = k0 + stride;
      v2f a0r = sr[k0], a0i = si[k0], a1r = sr[k1], a1i = si[k1];
      sr[k0] = gr * a0r - gi * a0i + dr * a1r - di * a1i;
      si[k0] = gr * a0i + gi * a0r + dr * a1i + di * a1r;
      sr[k1] = gr * a1r + gi * a1i - dr * a0r - di * a0i;
      si[k1] = gr * a1i - gi * a1r - dr * a0i + di * a0r;
    }
  }
}

// CNOT(control C, target T): pure register permutation (fully unrolled).
template <int C, int T>
__device__ __forceinline__ void apply_cnot_(v2f (&sr)[16], v2f (&si)[16]) {
  constexpr int cb = 8 >> C, tb = 8 >> T;
#pragma unroll
  for (int k = 0; k < 16; ++k) {
    if ((k & cb) && !(k & tb)) {
      const int k2 = k | tb;
      v2f tr = sr[k]; sr[k] = sr[k2]; sr[k2] = tr;
      v2f ti = si[k]; si[k] = si[k2]; si[k2] = ti;
    }
  }
}

__global__ __launch_bounds__(256, 4) void qlayer_main(const float* __restrict__ x,
                                                      const float* __restrict__ w,
                                                      float* __restrict__ out) {
  // ---- Fused precompute: M = RZ(pz)*RY(py) per (layer, wire); layer 3 uses
  // RZ = I (exact: diagonal phase before the final CNOT block is
  // probability-invariant). Splatted v2f quads {ar,ai,br,bi} in LDS. ----
  __shared__ v2f Msh[16 * 4];
  int tid = threadIdx.x;
  if (tid < 16) {
    int l = tid >> 2, q = tid & 3;
    float ay = 0.5f * w[8 * l + q];                       // RY angle /2
    float az = (l == 3) ? 0.0f : 0.5f * w[8 * l + 4 + q]; // RZ angle /2 (I on l=3)
    float cy, sy, cz, sz;
    __sincosf(ay, &sy, &cy);
    __sincosf(az, &sz, &cz);
    float ar = cz * cy, ai = -sz * cy, br = -cz * sy, bi = sz * sy;
    Msh[tid * 4 + 0] = v2f{ar, ar};
    Msh[tid * 4 + 1] = v2f{ai, ai};
    Msh[tid * 4 + 2] = v2f{br, br};
    Msh[tid * 4 + 3] = v2f{bi, bi};
  }

  int t = blockIdx.x * blockDim.x + tid;  // owns batch elems 2t, 2t+1
  float4 xv0 = reinterpret_cast<const float4*>(x)[2 * t];
  float4 xv1 = reinterpret_cast<const float4*>(x)[2 * t + 1];
  v2f cx[4], sx[4];
  {
    float c, s;
    __sincosf(0.5f * xv0.x, &s, &c); sx[0].x = s; cx[0].x = c;
    __sincosf(0.5f * xv0.y, &s, &c); sx[1].x = s; cx[1].x = c;
    __sincosf(0.5f * xv0.z, &s, &c); sx[2].x = s; cx[2].x = c;
    __sincosf(0.5f * xv0.w, &s, &c); sx[3].x = s; cx[3].x = c;
    __sincosf(0.5f * xv1.x, &s, &c); sx[0].y = s; cx[0].y = c;
    __sincosf(0.5f * xv1.y, &s, &c); sx[1].y = s; cx[1].y = c;
    __sincosf(0.5f * xv1.z, &s, &c); sx[2].y = s; cx[2].y = c;
    __sincosf(0.5f * xv1.w, &s, &c); sx[3].y = s; cx[3].y = c;
  }

  __syncthreads();  // Msh ready

  v2f sr[16], si[16];

  // ---- Layer 0 on |0000>: product state, built IN-PLACE LSB-first.
  // bit=0 branch * g; bit=1 branch * -conj(d) = (-dr,+di):
  //   re = -dr*ar - di*ai,   im = di*ar - dr*ai. ----
  {
    v2f gr, gi, dr, di;
    make_g2(Msh, 3, cx[3], sx[3], gr, gi, dr, di);
    sr[0] = gr;  si[0] = gi;
    sr[1] = -dr; si[1] = di;
    make_g2(Msh, 2, cx[2], sx[2], gr, gi, dr, di);
#pragma unroll
    for (int k = 1; k >= 0; --k) {
      v2f ar_ = sr[k], ai_ = si[k];
      sr[k + 2] = -(dr * ar_) - di * ai_;
      si[k + 2] = di * ar_ - dr * ai_;
      sr[k]     = gr * ar_ - gi * ai_;
      si[k]     = gr * ai_ + gi * ar_;
    }
    make_g2(Msh, 1, cx[1], sx[1], gr, gi, dr, di);
#pragma unroll
    for (int k = 3; k >= 0; --k) {
      v2f ar_ = sr[k], ai_ = si[k];
      sr[k + 4] = -(dr * ar_) - di * ai_;
      si[k + 4] = di * ar_ - dr * ai_;
      sr[k]     = gr * ar_ - gi * ai_;
      si[k]     = gr * ai_ + gi * ar_;
    }
    make_g2(Msh, 0, cx[0], sx[0], gr, gi, dr, di);
#pragma unroll
    for (int k = 7; k >= 0; --k) {
      v2f ar_ = sr[k], ai_ = si[k];
      sr[k + 8] = -(dr * ar_) - di * ai_;
      si[k + 8] = di * ar_ - dr * ai_;
      sr[k]     = gr * ar_ - gi * ai_;
      si[k]     = gr * ai_ + gi * ar_;
    }
  }
  apply_cnot_<2, 3>(sr, si);
  apply_cnot_<1, 2>(sr, si);
  apply_cnot_<0, 1>(sr, si);
  apply_cnot_<3, 0>(sr, si);

  // ---- Layers 1..2 (fully unrolled: CNOTs stay register renames) ----
#pragma unroll
  for (int l = 1; l < 3; ++l) {
    v2f gr, gi, dr, di;
    make_g2(Msh, l * 4 + 0, cx[0], sx[0], gr, gi, dr, di);
    apply_su2<0>(sr, si, gr, gi, dr, di);
    make_g2(Msh, l * 4 + 1, cx[1], sx[1], gr, gi, dr, di);
    apply_su2<1>(sr, si, gr, gi, dr, di);
    make_g2(Msh, l * 4 + 2, cx[2], sx[2], gr, gi, dr, di);
    apply_su2<2>(sr, si, gr, gi, dr, di);
    make_g2(Msh, l * 4 + 3, cx[3], sx[3], gr, gi, dr, di);
    apply_su2<3>(sr, si, gr, gi, dr, di);
    apply_cnot_<2, 3>(sr, si);
    apply_cnot_<1, 2>(sr, si);
    apply_cnot_<0, 1>(sr, si);
    apply_cnot_<3, 0>(sr, si);
  }

  // ---- Layer 3: M real (RZ folded out) ----
  {
    v2f gr, gi, dr, di;
    make_g2_real(Msh, 12, cx[0], sx[0], gr, gi, dr, di);
    apply_su2<0>(sr, si, gr, gi, dr, di);
    make_g2_real(Msh, 13, cx[1], sx[1], gr, gi, dr, di);
    apply_su2<1>(sr, si, gr, gi, dr, di);
    make_g2_real(Msh, 14, cx[2], sx[2], gr, gi, dr, di);
    apply_su2<2>(sr, si, gr, gi, dr, di);
    make_g2_real(Msh, 15, cx[3], sx[3], gr, gi, dr, di);
    apply_su2<3>(sr, si, gr, gi, dr, di);
    apply_cnot_<2, 3>(sr, si);
    apply_cnot_<1, 2>(sr, si);
    apply_cnot_<0, 1>(sr, si);
    apply_cnot_<3, 0>(sr, si);
  }

  // ---- Measurement, register-frugal: fold |amp|^2 into the first butterfly
  // level so sr/si pairs die as they are consumed (no live p[16]).
  // o_i = sum_k p_k * (bit(3-i)?-1:+1). ----
  v2f s2[8], d2[8];
#pragma unroll
  for (int k = 0; k < 8; ++k) {
    v2f p0 = sr[2 * k]     * sr[2 * k]     + si[2 * k]     * si[2 * k];
    v2f p1 = sr[2 * k + 1] * sr[2 * k + 1] + si[2 * k + 1] * si[2 * k + 1];
    s2[k] = p0 + p1;
    d2[k] = p0 - p1;
  }
  v2f o3 = ((d2[0] + d2[1]) + (d2[2] + d2[3])) + ((d2[4] + d2[5]) + (d2[6] + d2[7]));
  v2f s4[4], d4[4];
#pragma unroll
  for (int k = 0; k < 4; ++k) {
    s4[k] = s2[2 * k] + s2[2 * k + 1];
    d4[k] = s2[2 * k] - s2[2 * k + 1];
  }
  v2f o2 = (d4[0] + d4[1]) + (d4[2] + d4[3]);
  v2f s8a = s4[0] + s4[1], s8b = s4[2] + s4[3];
  v2f d8a = s4[0] - s4[1], d8b = s4[2] - s4[3];
  v2f o1 = d8a + d8b;
  v2f o0 = s8a - s8b;

  float4* o4 = reinterpret_cast<float4*>(out);
  o4[2 * t]     = make_float4(o0.x, o1.x, o2.x, o3.x);
  o4[2 * t + 1] = make_float4(o0.y, o1.y, o2.y, o3.y);
}

extern "C" void kernel_launch(void* const* d_in, const int* in_sizes, int n_in,
                              void* d_out, int out_size, void* d_ws, size_t ws_size,
                              hipStream_t stream) {
  const float* x = (const float*)d_in[0];
  const float* w = (const float*)d_in[1];
  float* out = (float*)d_out;
  int nb = in_sizes[0] / 4;
  int np = nb / 2;           // 2 elements per thread; B=524288 -> np=262144

  int blocks = np / 256;     // exact: 1024 blocks
  hipLaunchKernelGGL(qlayer_main, dim3(blocks), dim3(256), 0, stream, x, w, out);
}